// Round 7
// baseline (187.584 us; speedup 1.0000x reference)
//
#include <hip/hip_runtime.h>
#include <math.h>

#define NEG_SLOPE 0.2f
#define PB 256        // partition blocks (fixed chunking shared by hist/scatter)
#define BKT_SHIFT 8   // 256 nodes per bucket
#define WSLICES 8     // blocks per bucket in compute_w

typedef __attribute__((ext_vector_type(8))) short bf16x8;
typedef __attribute__((ext_vector_type(4))) float f32x4;

__device__ __forceinline__ unsigned bf16_rne(float f) {
  unsigned u = __float_as_uint(f);
  return (u + 0x7fff + ((u >> 16) & 1)) >> 16;
}

__device__ __forceinline__ float lrelu_exp(float v) {
  v = v > 0.f ? v : NEG_SLOPE * v;
  return __expf(v);  // no max-subtraction: |v| <~ 10, fp32-safe; normalized
                     // by the denominator so it matches the reference softmax
}

// fc_w fp32[128][128] -> bf16-pair words [128][64], once.
__global__ void fc_conv(const float* __restrict__ fc_w,
                        unsigned* __restrict__ fc_wb, int n) {
  const int i = blockIdx.x * 256 + threadIdx.x;
  if (i < n) {
    const float2 v = reinterpret_cast<const float2*>(fc_w)[i];
    fc_wb[i] = bf16_rne(v.x) | (bf16_rne(v.y) << 16);
  }
}

// ---------------------------------------------------------------------------
// LDS-free MFMA GEMM: feat = x @ fc_w^T, bf16 inputs, fp32 accumulate.
// Block = 256 thr (4 waves), 64 node-rows per block. A frags loaded straight
// from fp32 x (pack inline); B frags loaded from pre-converted fc_wb, which
// is 32KB -> L1-resident. Wave w: rows w*16..+15 x all 128 cols (8 col-tiles
// of 16), K=128 as 4 MFMA(16x16x32) per tile. A/B share the same
// (g=lane>>4, j)->k convention so any hw k-permutation cancels.
// C/D: col=lane&15, row=(lane>>4)*4+reg (m89-verified).
// ---------------------------------------------------------------------------
__global__ __launch_bounds__(256) void gemm_feat_attn(
    const float* __restrict__ x, const unsigned* __restrict__ fc_wb,
    const float* __restrict__ attn_l, const float* __restrict__ attn_r,
    unsigned* __restrict__ featb, float* __restrict__ el,
    float* __restrict__ er, int N)
{
  const int t = threadIdx.x;
  const int w = t >> 6;         // wave id 0..3
  const int l = t & 63;
  const int cl = l & 15;        // free index (A row / B col / D col)
  const int g = l >> 4;         // k-group
  const int row_base = blockIdx.x * 64;
  const int arow = min(row_base + w * 16 + cl, N - 1);
  const float* __restrict__ xp = x + (size_t)arow * 128;

  bf16x8 a_frag[4];
#pragma unroll
  for (int ks = 0; ks < 4; ++ks) {
    const float4 v0 = *reinterpret_cast<const float4*>(xp + ks * 32 + g * 8);
    const float4 v1 =
        *reinterpret_cast<const float4*>(xp + ks * 32 + g * 8 + 4);
    uint4 uu;
    uu.x = bf16_rne(v0.x) | (bf16_rne(v0.y) << 16);
    uu.y = bf16_rne(v0.z) | (bf16_rne(v0.w) << 16);
    uu.z = bf16_rne(v1.x) | (bf16_rne(v1.y) << 16);
    uu.w = bf16_rne(v1.z) | (bf16_rne(v1.w) << 16);
    a_frag[ks] = *reinterpret_cast<bf16x8*>(&uu);
  }

  f32x4 acc[8];
#pragma unroll
  for (int ct = 0; ct < 8; ++ct) acc[ct] = (f32x4){0.f, 0.f, 0.f, 0.f};

#pragma unroll
  for (int ct = 0; ct < 8; ++ct) {
#pragma unroll
    for (int ks = 0; ks < 4; ++ks) {
      const bf16x8 b_frag = *reinterpret_cast<const bf16x8*>(
          &fc_wb[(ct * 16 + cl) * 64 + ks * 16 + g * 4]);
      acc[ct] = __builtin_amdgcn_mfma_f32_16x16x32_bf16(a_frag[ks], b_frag,
                                                        acc[ct], 0, 0, 0);
    }
  }

  // featb store: lane holds D[row=g*4+r][col=ct*16+cl]; pair (even,odd cl)
#pragma unroll
  for (int ct = 0; ct < 8; ++ct) {
#pragma unroll
    for (int r = 0; r < 4; ++r) {
      const float v = acc[ct][r];
      const float vn = __shfl_xor(v, 1);
      const int node = row_base + w * 16 + g * 4 + r;
      if ((cl & 1) == 0 && node < N) {
        featb[(size_t)node * 64 + ct * 8 + (cl >> 1)] =
            bf16_rne(v) | (bf16_rne(vn) << 16);
      }
    }
  }

  // el/er epilogue: col 2h*16+cl -> (head h, d=cl); (2h+1)*16+cl -> d=16+cl.
  float al_lo[4], al_hi[4], ar_lo[4], ar_hi[4];
#pragma unroll
  for (int h = 0; h < 4; ++h) {
    al_lo[h] = attn_l[h * 32 + cl];
    al_hi[h] = attn_l[h * 32 + 16 + cl];
    ar_lo[h] = attn_r[h * 32 + cl];
    ar_hi[h] = attn_r[h * 32 + 16 + cl];
  }
#pragma unroll
  for (int r = 0; r < 4; ++r) {
    const int node = row_base + w * 16 + g * 4 + r;
#pragma unroll
    for (int h = 0; h < 4; ++h) {
      float pl = acc[2 * h][r] * al_lo[h] + acc[2 * h + 1][r] * al_hi[h];
      float pr = acc[2 * h][r] * ar_lo[h] + acc[2 * h + 1][r] * ar_hi[h];
#pragma unroll
      for (int d = 1; d < 16; d <<= 1) {
        pl += __shfl_xor(pl, d);
        pr += __shfl_xor(pr, d);
      }
      if (cl == 0 && node < N) {
        el[(size_t)node * 4 + h] = pl;
        er[(size_t)node * 4 + h] = pr;
      }
    }
  }
}

// ---------------------------------------------------------------------------
// CSR build, two-level binning. Bucket = 256 consecutive dst nodes (NB=391).
// ---------------------------------------------------------------------------
__global__ __launch_bounds__(256) void hist_bucket(const int* __restrict__ dst,
                                                   int* __restrict__ hist,
                                                   int E, int NB, int chunk) {
  __shared__ int h[512];
  const int k = blockIdx.x, t = threadIdx.x;
  for (int i = t; i < NB; i += 256) h[i] = 0;
  __syncthreads();
  const int beg = k * chunk, end = min(E, beg + chunk);
  for (int e = beg + t; e < end; e += 256)
    atomicAdd(&h[dst[e] >> BKT_SHIFT], 1);
  __syncthreads();
  for (int i = t; i < NB; i += 256) hist[i * PB + k] = h[i];
}

__global__ __launch_bounds__(256) void scan_a(const int* __restrict__ deg,
                                              int* __restrict__ offs,
                                              int* __restrict__ blk_sums,
                                              int n) {
  __shared__ int wsum[4];
  const int b = blockIdx.x, t = threadIdx.x;
  const int base = b * 2048 + t * 8;
  int v[8];
  int s = 0;
#pragma unroll
  for (int j = 0; j < 8; ++j) {
    v[j] = s;
    const int d = (base + j < n) ? deg[base + j] : 0;
    s += d;
  }
  const int lane = t & 63;
  int incl = s;
#pragma unroll
  for (int d = 1; d < 64; d <<= 1) {
    const int o = __shfl_up(incl, d);
    if (lane >= d) incl += o;
  }
  const int w = t >> 6;
  if (lane == 63) wsum[w] = incl;
  __syncthreads();
  int woff = 0;
  for (int ww = 0; ww < w; ++ww) woff += wsum[ww];
  const int thr_excl = woff + incl - s;
#pragma unroll
  for (int j = 0; j < 8; ++j)
    if (base + j < n) offs[base + j] = thr_excl + v[j];
  if (t == 255) blk_sums[b] = woff + incl;
}

__global__ void scan_b(const int* __restrict__ blk_sums,
                       int* __restrict__ blk_off, int* __restrict__ offs,
                       int n, int nb) {
  const int lane = threadIdx.x & 63;
  int v = (lane < nb) ? blk_sums[lane] : 0;
  int incl = v;
#pragma unroll
  for (int d = 1; d < 64; d <<= 1) {
    const int o = __shfl_up(incl, d);
    if (lane >= d) incl += o;
  }
  if (lane < nb) blk_off[lane] = incl - v;
  if (lane == 63) offs[n] = incl;
}

// Partition edges into bucket-contiguous regions; per-(bucket,block) region is
// exclusive to this block. Edge packed in 4B: src(20b) | local_dst(8b)<<20.
// hscan is chunk-local; the global base is blk_off[idx>>11] added on read
// (scan_c pass eliminated).
__global__ __launch_bounds__(256) void part_scatter(
    const int* __restrict__ src, const int* __restrict__ dst,
    const int* __restrict__ hscan, const int* __restrict__ blk_off,
    unsigned* __restrict__ part, int E, int NB, int chunk) {
  __shared__ int cur[512];
  const int k = blockIdx.x, t = threadIdx.x;
  for (int i = t; i < NB; i += 256) {
    const int m = i * PB + k;
    cur[i] = hscan[m] + blk_off[m >> 11];
  }
  __syncthreads();
  const int beg = k * chunk, end = min(E, beg + chunk);
  for (int e = beg + t; e < end; e += 256) {
    const int d = dst[e];
    const int b = d >> BKT_SHIFT;
    const int pos = atomicAdd(&cur[b], 1);
    part[pos] = (unsigned)src[e] |
                ((unsigned)(d & ((1 << BKT_SHIFT) - 1)) << 20);
  }
}

// One block per bucket: LDS count -> scan -> cursor scatter of the PACKED
// word into CSR order. Pure permutation; no per-edge math here.
__global__ __launch_bounds__(256) void build_csr(
    const unsigned* __restrict__ part, const int* __restrict__ hscan,
    const int* __restrict__ blk_off, int* __restrict__ node_offs,
    unsigned* __restrict__ csr, int N, int E, int NB) {
  __shared__ int cnt[256];
  __shared__ int wtot[4];
  const int b = blockIdx.x, t = threadIdx.x;
  const int m0 = b * PB;
  const int bbase = hscan[m0] + blk_off[m0 >> 11];
  int bend = E;
  if (b + 1 < NB) {
    const int m1 = (b + 1) * PB;
    bend = hscan[m1] + blk_off[m1 >> 11];
  }
  const int node0 = b << BKT_SHIFT;
  cnt[t] = 0;
  __syncthreads();
  for (int p = bbase + t; p < bend; p += 256)
    atomicAdd(&cnt[part[p] >> 20], 1);
  __syncthreads();
  const int a0 = cnt[t];
  int incl = a0;
#pragma unroll
  for (int d1 = 1; d1 < 64; d1 <<= 1) {
    const int o = __shfl_up(incl, d1);
    if ((t & 63) >= d1) incl += o;
  }
  const int w = t >> 6;
  if ((t & 63) == 63) wtot[w] = incl;
  __syncthreads();
  int woff = 0;
  for (int ww = 0; ww < w; ++ww) woff += wtot[ww];
  const int e0 = woff + incl - a0;  // exclusive offset of node t
  cnt[t] = e0;                      // reuse as cursor
  if (node0 + t < N) node_offs[node0 + t] = bbase + e0;
  if (b == NB - 1 && t == 0) node_offs[N] = E;
  __syncthreads();
  for (int p = bbase + t; p < bend; p += 256) {
    const unsigned v = part[p];
    const int lpos = atomicAdd(&cnt[v >> 20], 1);
    csr[bbase + lpos] = v;
  }
}

// Edge-parallel over CSR order: w[h][pos] = exp(lrelu(el[s][h]+er[d][h])),
// fp32 SoA (coalesced writes; broadcast-friendly reads in agg).
__global__ __launch_bounds__(256) void compute_w(
    const unsigned* __restrict__ csr, const int* __restrict__ hscan,
    const int* __restrict__ blk_off, const float* __restrict__ el,
    const float* __restrict__ er, float* __restrict__ wsoa, int E, int NB) {
  const int b = blockIdx.x / WSLICES;
  const int sl = blockIdx.x - b * WSLICES;
  const int m0 = b * PB;
  const int bbase = hscan[m0] + blk_off[m0 >> 11];
  int bend = E;
  if (b + 1 < NB) {
    const int m1 = (b + 1) * PB;
    bend = hscan[m1] + blk_off[m1 >> 11];
  }
  const int node0 = b << BKT_SHIFT;
  const int len = bend - bbase;
  const int per = (len + WSLICES - 1) / WSLICES;
  const int s0 = bbase + sl * per;
  const int s1 = min(bend, s0 + per);
  for (int pos = s0 + (int)threadIdx.x; pos < s1; pos += 256) {
    const unsigned v = csr[pos];
    const unsigned s = v & 0xFFFFFu;
    const unsigned ld = v >> 20;
    const float4 l4 = *reinterpret_cast<const float4*>(el + s * 4);
    const float4 r4 =
        *reinterpret_cast<const float4*>(er + (unsigned)(node0 + ld) * 4);
    wsoa[pos]         = lrelu_exp(l4.x + r4.x);
    wsoa[E + pos]     = lrelu_exp(l4.y + r4.y);
    wsoa[2 * E + pos] = lrelu_exp(l4.z + r4.z);
    wsoa[3 * E + pos] = lrelu_exp(l4.w + r4.w);
  }
}

// ---------------------------------------------------------------------------
// Pull aggregation: one wave per destination node. Lane l owns output elems
// {2l, 2l+1} (one bf16x2 word), head h = l>>4. Body = full 8-edge groups
// (no predication); one predicated group handles the remainder. All 32-bit
// index math.
// ---------------------------------------------------------------------------
__global__ __launch_bounds__(256) void agg_kernel(
    const unsigned* __restrict__ featb, const unsigned* __restrict__ csr,
    const float* __restrict__ wsoa, const float* __restrict__ x,
    const float* __restrict__ bias, const int* __restrict__ node_offs,
    float* __restrict__ out, int N, int E)
{
  const int n = (int)((blockIdx.x * (size_t)blockDim.x + threadIdx.x) >> 6);
  if (n >= N) return;
  const unsigned lane = threadIdx.x & 63;
  const unsigned h = lane >> 4;
  const float* __restrict__ wrow = wsoa + h * (unsigned)E;
  const int beg = node_offs[n];
  const int end = node_offs[n + 1];
  const int nfull = (end - beg) >> 3;

  float ax = 0.f, ay = 0.f, ds = 0.f;
  int p = beg;
  for (int gi = 0; gi < nfull; ++gi, p += 8) {
    unsigned pk[8]; float wv[8]; unsigned fv[8];
#pragma unroll
    for (int j = 0; j < 8; ++j) pk[j] = csr[(unsigned)(p + j)];
#pragma unroll
    for (int j = 0; j < 8; ++j) wv[j] = wrow[(unsigned)(p + j)];
#pragma unroll
    for (int j = 0; j < 8; ++j)
      fv[j] = featb[(pk[j] & 0xFFFFFu) * 64u + lane];
#pragma unroll
    for (int j = 0; j < 8; ++j) {
      ax = fmaf(wv[j], __uint_as_float(fv[j] << 16), ax);
      ay = fmaf(wv[j], __uint_as_float(fv[j] & 0xffff0000u), ay);
      ds += wv[j];
    }
  }
  if (p < end) {  // single predicated group for the remainder (<8 edges)
    const int last = end - 1;
    int ev[8]; unsigned pk[8]; float wv[8]; unsigned fv[8];
#pragma unroll
    for (int j = 0; j < 8; ++j) ev[j] = min(p + j, last);
#pragma unroll
    for (int j = 0; j < 8; ++j) pk[j] = csr[(unsigned)ev[j]];
#pragma unroll
    for (int j = 0; j < 8; ++j) wv[j] = wrow[(unsigned)ev[j]];
#pragma unroll
    for (int j = 0; j < 8; ++j)
      fv[j] = featb[(pk[j] & 0xFFFFFu) * 64u + lane];
#pragma unroll
    for (int j = 0; j < 8; ++j) {
      if (p + j > last) wv[j] = 0.f;
      ax = fmaf(wv[j], __uint_as_float(fv[j] << 16), ax);
      ay = fmaf(wv[j], __uint_as_float(fv[j] & 0xffff0000u), ay);
      ds += wv[j];
    }
  }

  const float inv = 1.f / fmaxf(ds, 1e-38f);
  const float2 xr = ((const float2*)x)[(unsigned)n * 64 + lane];
  const float2 br = ((const float2*)bias)[lane];
  float2 o;
  o.x = fmaf(ax, inv, xr.x + br.x);
  o.y = fmaf(ay, inv, xr.y + br.y);
  ((float2*)out)[(unsigned)n * 64 + lane] = o;
}

// ---------------------------------------------------------------------------
extern "C" void kernel_launch(void* const* d_in, const int* in_sizes, int n_in,
                              void* d_out, int out_size, void* d_ws,
                              size_t ws_size, hipStream_t stream) {
  const float* x      = (const float*)d_in[0];
  const float* fc_w   = (const float*)d_in[1];
  const float* attn_l = (const float*)d_in[2];
  const float* attn_r = (const float*)d_in[3];
  const float* bias   = (const float*)d_in[4];
  const int*   src    = (const int*)d_in[5];
  const int*   dst    = (const int*)d_in[6];
  const int N = in_sizes[0] / 128;
  const int E = in_sizes[5];
  float* out = (float*)d_out;

  const int NB = (N + 255) >> 8;        // 391 buckets (NB <= 512 assumed)
  const int M = NB * PB;                // hist entries
  const int chunk = (E + PB - 1) / PB;  // edges per partition block

  char* ws = (char*)d_ws;
  size_t off = 0;
  auto alloc = [&](size_t bytes) {
    void* p = ws + off;
    off += (bytes + 255) & ~(size_t)255;
    return p;
  };
  unsigned* featb   = (unsigned*)alloc((size_t)N * 128 * 2);
  unsigned* fc_wb   = (unsigned*)alloc(128 * 64 * 4);
  float* el         = (float*)alloc((size_t)N * 4 * 4);
  float* er         = (float*)alloc((size_t)N * 4 * 4);
  int*   hist       = (int*)alloc((size_t)M * 4);
  int*   hscan      = (int*)alloc((size_t)(M + 1) * 4);
  int*   node_offs  = (int*)alloc((size_t)(N + 1) * 4);
  int*   blk_sums   = (int*)alloc(256);
  int*   blk_off    = (int*)alloc(256);
  unsigned* part    = (unsigned*)alloc((size_t)E * 4);
  unsigned* csr     = (unsigned*)alloc((size_t)E * 4);
  float* wsoa       = (float*)alloc((size_t)E * 4 * 4);

  fc_conv<<<32, 256, 0, stream>>>(fc_w, fc_wb, 128 * 64);
  gemm_feat_attn<<<(N + 63) / 64, 256, 0, stream>>>(x, fc_wb, attn_l, attn_r,
                                                    featb, el, er, N);
  hist_bucket<<<PB, 256, 0, stream>>>(dst, hist, E, NB, chunk);
  const int nb = (M + 2047) / 2048;  // 49 (must be <= 64)
  scan_a<<<nb, 256, 0, stream>>>(hist, hscan, blk_sums, M);
  scan_b<<<1, 64, 0, stream>>>(blk_sums, blk_off, hscan, M, nb);
  part_scatter<<<PB, 256, 0, stream>>>(src, dst, hscan, blk_off, part, E, NB,
                                       chunk);
  build_csr<<<NB, 256, 0, stream>>>(part, hscan, blk_off, node_offs, csr, N,
                                    E, NB);
  compute_w<<<NB * WSLICES, 256, 0, stream>>>(csr, hscan, blk_off, el, er,
                                              wsoa, E, NB);
  agg_kernel<<<(N + 3) / 4, 256, 0, stream>>>(featb, csr, wsoa, x, bias,
                                              node_offs, out, N, E);
}

// Round 8
// 170.148 us; speedup vs baseline: 1.1025x; 1.1025x over previous
//
#include <hip/hip_runtime.h>
#include <math.h>

#define NEG_SLOPE 0.2f
#define PB 256        // partition blocks (fixed chunking shared by hist/scatter)
#define BKT_SHIFT 8   // 256 nodes per bucket
#define WSLICES 8     // blocks per bucket in compute_w

typedef __attribute__((ext_vector_type(8))) short bf16x8;
typedef __attribute__((ext_vector_type(4))) float f32x4;

__device__ __forceinline__ unsigned bf16_rne(float f) {
  unsigned u = __float_as_uint(f);
  return (u + 0x7fff + ((u >> 16) & 1)) >> 16;
}

__device__ __forceinline__ float lrelu_exp(float v) {
  v = v > 0.f ? v : NEG_SLOPE * v;
  return __expf(v);  // no max-subtraction: |v| <~ 10, fp32-safe; normalized
                     // by the denominator so it matches the reference softmax
}

// fc_w fp32[128][128] -> bf16-pair words [128][64], once.
__global__ void fc_conv(const float* __restrict__ fc_w,
                        unsigned* __restrict__ fc_wb, int n) {
  const int i = blockIdx.x * 256 + threadIdx.x;
  if (i < n) {
    const float2 v = reinterpret_cast<const float2*>(fc_w)[i];
    fc_wb[i] = bf16_rne(v.x) | (bf16_rne(v.y) << 16);
  }
}

// ---------------------------------------------------------------------------
// MFMA GEMM (LDS-staged, R6 structure): feat = x @ fc_w^T, bf16 in, fp32 acc.
// Block = 256 thr (4 waves), 64 node-rows. B staged by word-copy from the
// pre-converted fc_wb (32KB); x staged fp32->bf16. LDS rows padded to 68.
// Wave w: rows w*16..+15 x 128 cols (8 col-tiles of 16), K=128 as 4
// MFMA(16x16x32). A/B share the same (g=lane>>4, j)->k convention so any hw
// k-permutation cancels. C/D: col=lane&15, row=(lane>>4)*4+reg (m89-verified).
// ---------------------------------------------------------------------------
__global__ __launch_bounds__(256) void gemm_feat_attn(
    const float* __restrict__ x, const unsigned* __restrict__ fc_wb,
    const float* __restrict__ attn_l, const float* __restrict__ attn_r,
    unsigned* __restrict__ featb, float* __restrict__ el,
    float* __restrict__ er, int N)
{
  __shared__ __align__(16) unsigned x_lds[64 * 68];
  __shared__ __align__(16) unsigned w_lds[128 * 68];
  const int t = threadIdx.x;
  const int row_base = blockIdx.x * 64;

  // stage fc_wb words (coalesced uint4): 2048 uint4 total, 8 per thread
  {
    const uint4* fb4 = reinterpret_cast<const uint4*>(fc_wb);
#pragma unroll
    for (int k = 0; k < 8; ++k) {
      const int i4 = t + k * 256;
      const uint4 v = fb4[i4];
      const int row = i4 >> 4;        // 16 uint4 per 64-word row
      unsigned* d = &w_lds[row * 68 + (i4 & 15) * 4];
      d[0] = v.x; d[1] = v.y; d[2] = v.z; d[3] = v.w;
    }
  }
  // stage x rows -> bf16 pairs: thread t covers row r=t>>2, quarter (t&3)*32
  {
    const int r = t >> 2, q = t & 3;
    const int grow = min(row_base + r, N - 1);
    const float* src = x + (size_t)grow * 128 + q * 32;
    unsigned* dstp = &x_lds[r * 68 + q * 16];
#pragma unroll
    for (int i = 0; i < 8; ++i) {
      const float4 v = *reinterpret_cast<const float4*>(src + i * 4);
      dstp[2 * i]     = bf16_rne(v.x) | (bf16_rne(v.y) << 16);
      dstp[2 * i + 1] = bf16_rne(v.z) | (bf16_rne(v.w) << 16);
    }
  }
  __syncthreads();

  const int w = t >> 6;         // wave id 0..3
  const int l = t & 63;
  const int cl = l & 15;        // free index (A row / B col / D col)
  const int g = l >> 4;         // k-group

  bf16x8 a_frag[4];
#pragma unroll
  for (int ks = 0; ks < 4; ++ks)
    a_frag[ks] = *reinterpret_cast<const bf16x8*>(
        &x_lds[(w * 16 + cl) * 68 + ks * 16 + g * 4]);

  f32x4 acc[8];
#pragma unroll
  for (int ct = 0; ct < 8; ++ct) acc[ct] = (f32x4){0.f, 0.f, 0.f, 0.f};

#pragma unroll
  for (int ct = 0; ct < 8; ++ct) {
#pragma unroll
    for (int ks = 0; ks < 4; ++ks) {
      const bf16x8 b_frag = *reinterpret_cast<const bf16x8*>(
          &w_lds[(ct * 16 + cl) * 68 + ks * 16 + g * 4]);
      acc[ct] = __builtin_amdgcn_mfma_f32_16x16x32_bf16(a_frag[ks], b_frag,
                                                        acc[ct], 0, 0, 0);
    }
  }

  // featb store: lane holds D[row=g*4+r][col=ct*16+cl]; pair (even,odd cl)
#pragma unroll
  for (int ct = 0; ct < 8; ++ct) {
#pragma unroll
    for (int r = 0; r < 4; ++r) {
      const float v = acc[ct][r];
      const float vn = __shfl_xor(v, 1);
      const int node = row_base + w * 16 + g * 4 + r;
      if ((cl & 1) == 0 && node < N) {
        featb[(size_t)node * 64 + ct * 8 + (cl >> 1)] =
            bf16_rne(v) | (bf16_rne(vn) << 16);
      }
    }
  }

  // el/er epilogue: col 2h*16+cl -> (head h, d=cl); (2h+1)*16+cl -> d=16+cl.
  float al_lo[4], al_hi[4], ar_lo[4], ar_hi[4];
#pragma unroll
  for (int h = 0; h < 4; ++h) {
    al_lo[h] = attn_l[h * 32 + cl];
    al_hi[h] = attn_l[h * 32 + 16 + cl];
    ar_lo[h] = attn_r[h * 32 + cl];
    ar_hi[h] = attn_r[h * 32 + 16 + cl];
  }
#pragma unroll
  for (int r = 0; r < 4; ++r) {
    const int node = row_base + w * 16 + g * 4 + r;
#pragma unroll
    for (int h = 0; h < 4; ++h) {
      float pl = acc[2 * h][r] * al_lo[h] + acc[2 * h + 1][r] * al_hi[h];
      float pr = acc[2 * h][r] * ar_lo[h] + acc[2 * h + 1][r] * ar_hi[h];
#pragma unroll
      for (int d = 1; d < 16; d <<= 1) {
        pl += __shfl_xor(pl, d);
        pr += __shfl_xor(pr, d);
      }
      if (cl == 0 && node < N) {
        el[(size_t)node * 4 + h] = pl;
        er[(size_t)node * 4 + h] = pr;
      }
    }
  }
}

// ---------------------------------------------------------------------------
// CSR build, two-level binning. Bucket = 256 consecutive dst nodes (NB=391).
// ---------------------------------------------------------------------------
__global__ __launch_bounds__(256) void hist_bucket(const int* __restrict__ dst,
                                                   int* __restrict__ hist,
                                                   int E, int NB, int chunk) {
  __shared__ int h[512];
  const int k = blockIdx.x, t = threadIdx.x;
  for (int i = t; i < NB; i += 256) h[i] = 0;
  __syncthreads();
  const int beg = k * chunk, end = min(E, beg + chunk);
  for (int e = beg + t; e < end; e += 256)
    atomicAdd(&h[dst[e] >> BKT_SHIFT], 1);
  __syncthreads();
  for (int i = t; i < NB; i += 256) hist[i * PB + k] = h[i];
}

__global__ __launch_bounds__(256) void scan_a(const int* __restrict__ deg,
                                              int* __restrict__ offs,
                                              int* __restrict__ blk_sums,
                                              int n) {
  __shared__ int wsum[4];
  const int b = blockIdx.x, t = threadIdx.x;
  const int base = b * 2048 + t * 8;
  int v[8];
  int s = 0;
#pragma unroll
  for (int j = 0; j < 8; ++j) {
    v[j] = s;
    const int d = (base + j < n) ? deg[base + j] : 0;
    s += d;
  }
  const int lane = t & 63;
  int incl = s;
#pragma unroll
  for (int d = 1; d < 64; d <<= 1) {
    const int o = __shfl_up(incl, d);
    if (lane >= d) incl += o;
  }
  const int w = t >> 6;
  if (lane == 63) wsum[w] = incl;
  __syncthreads();
  int woff = 0;
  for (int ww = 0; ww < w; ++ww) woff += wsum[ww];
  const int thr_excl = woff + incl - s;
#pragma unroll
  for (int j = 0; j < 8; ++j)
    if (base + j < n) offs[base + j] = thr_excl + v[j];
  if (t == 255) blk_sums[b] = woff + incl;
}

__global__ void scan_b(const int* __restrict__ blk_sums,
                       int* __restrict__ blk_off, int* __restrict__ offs,
                       int n, int nb) {
  const int lane = threadIdx.x & 63;
  int v = (lane < nb) ? blk_sums[lane] : 0;
  int incl = v;
#pragma unroll
  for (int d = 1; d < 64; d <<= 1) {
    const int o = __shfl_up(incl, d);
    if (lane >= d) incl += o;
  }
  if (lane < nb) blk_off[lane] = incl - v;
  if (lane == 63) offs[n] = incl;
}

// Partition edges into bucket-contiguous regions; per-(bucket,block) region is
// exclusive to this block. Edge packed in 4B: src(20b) | local_dst(8b)<<20.
// hscan is chunk-local; global base = blk_off[idx>>11] added on read.
__global__ __launch_bounds__(256) void part_scatter(
    const int* __restrict__ src, const int* __restrict__ dst,
    const int* __restrict__ hscan, const int* __restrict__ blk_off,
    unsigned* __restrict__ part, int E, int NB, int chunk) {
  __shared__ int cur[512];
  const int k = blockIdx.x, t = threadIdx.x;
  for (int i = t; i < NB; i += 256) {
    const int m = i * PB + k;
    cur[i] = hscan[m] + blk_off[m >> 11];
  }
  __syncthreads();
  const int beg = k * chunk, end = min(E, beg + chunk);
  for (int e = beg + t; e < end; e += 256) {
    const int d = dst[e];
    const int b = d >> BKT_SHIFT;
    const int pos = atomicAdd(&cur[b], 1);
    part[pos] = (unsigned)src[e] |
                ((unsigned)(d & ((1 << BKT_SHIFT) - 1)) << 20);
  }
}

// One block per bucket: LDS count -> scan -> cursor scatter of the PACKED
// word into CSR order. Pure permutation; no per-edge math here.
__global__ __launch_bounds__(256) void build_csr(
    const unsigned* __restrict__ part, const int* __restrict__ hscan,
    const int* __restrict__ blk_off, int* __restrict__ node_offs,
    unsigned* __restrict__ csr, int N, int E, int NB) {
  __shared__ int cnt[256];
  __shared__ int wtot[4];
  const int b = blockIdx.x, t = threadIdx.x;
  const int m0 = b * PB;
  const int bbase = hscan[m0] + blk_off[m0 >> 11];
  int bend = E;
  if (b + 1 < NB) {
    const int m1 = (b + 1) * PB;
    bend = hscan[m1] + blk_off[m1 >> 11];
  }
  const int node0 = b << BKT_SHIFT;
  cnt[t] = 0;
  __syncthreads();
  for (int p = bbase + t; p < bend; p += 256)
    atomicAdd(&cnt[part[p] >> 20], 1);
  __syncthreads();
  const int a0 = cnt[t];
  int incl = a0;
#pragma unroll
  for (int d1 = 1; d1 < 64; d1 <<= 1) {
    const int o = __shfl_up(incl, d1);
    if ((t & 63) >= d1) incl += o;
  }
  const int w = t >> 6;
  if ((t & 63) == 63) wtot[w] = incl;
  __syncthreads();
  int woff = 0;
  for (int ww = 0; ww < w; ++ww) woff += wtot[ww];
  const int e0 = woff + incl - a0;  // exclusive offset of node t
  cnt[t] = e0;                      // reuse as cursor
  if (node0 + t < N) node_offs[node0 + t] = bbase + e0;
  if (b == NB - 1 && t == 0) node_offs[N] = E;
  __syncthreads();
  for (int p = bbase + t; p < bend; p += 256) {
    const unsigned v = part[p];
    const int lpos = atomicAdd(&cnt[v >> 20], 1);
    csr[bbase + lpos] = v;
  }
}

// Edge-parallel over CSR order: wsb[pos] = float4 of per-head numerators
// exp(lrelu(el[s][h]+er[d][h])) (AoS: one 16B line per edge).
__global__ __launch_bounds__(256) void compute_w(
    const unsigned* __restrict__ csr, const int* __restrict__ hscan,
    const int* __restrict__ blk_off, const float* __restrict__ el,
    const float* __restrict__ er, float4* __restrict__ wsb, int E, int NB) {
  const int b = blockIdx.x / WSLICES;
  const int sl = blockIdx.x - b * WSLICES;
  const int m0 = b * PB;
  const int bbase = hscan[m0] + blk_off[m0 >> 11];
  int bend = E;
  if (b + 1 < NB) {
    const int m1 = (b + 1) * PB;
    bend = hscan[m1] + blk_off[m1 >> 11];
  }
  const int node0 = b << BKT_SHIFT;
  const int len = bend - bbase;
  const int per = (len + WSLICES - 1) / WSLICES;
  const int s0 = bbase + sl * per;
  const int s1 = min(bend, s0 + per);
  for (int pos = s0 + (int)threadIdx.x; pos < s1; pos += 256) {
    const unsigned v = csr[pos];
    const unsigned s = v & 0xFFFFFu;
    const unsigned ld = v >> 20;
    const float4 l4 = *reinterpret_cast<const float4*>(el + s * 4);
    const float4 r4 =
        *reinterpret_cast<const float4*>(er + (unsigned)(node0 + ld) * 4);
    float4 wv;
    wv.x = lrelu_exp(l4.x + r4.x);
    wv.y = lrelu_exp(l4.y + r4.y);
    wv.z = lrelu_exp(l4.z + r4.z);
    wv.w = lrelu_exp(l4.w + r4.w);
    wsb[pos] = wv;
  }
}

// ---------------------------------------------------------------------------
// Pull aggregation, half-wave 2-edges/iter: wave per node; lane l =
// (half=l>>5, li=l&31). Lane li owns elems {4li..4li+3} (uint2 of featb;
// head = li>>3); half h processes edges p+2i+h. Halves combined once per
// node via shfl_xor(32). Body = 8-edge groups, one predicated tail group.
// ---------------------------------------------------------------------------
__global__ __launch_bounds__(256) void agg_kernel(
    const uint2* __restrict__ featb2, const unsigned* __restrict__ csr,
    const float* __restrict__ wf, const float* __restrict__ x,
    const float* __restrict__ bias, const int* __restrict__ node_offs,
    float* __restrict__ out, int N, int E)
{
  const int n = (int)((blockIdx.x * (size_t)blockDim.x + threadIdx.x) >> 6);
  if (n >= N) return;
  const unsigned lane = threadIdx.x & 63;
  const unsigned half = lane >> 5;
  const unsigned li = lane & 31;
  const unsigned hh = li >> 3;        // head of this lane's 4 elems
  const int beg = node_offs[n];
  const int end = node_offs[n + 1];
  const int nfull = (end - beg) >> 3;

  float a0 = 0.f, a1 = 0.f, a2 = 0.f, a3 = 0.f, ds = 0.f;
  int p = beg;
  for (int gi = 0; gi < nfull; ++gi, p += 8) {
    unsigned pk[4]; float wv[4]; uint2 fv[4];
#pragma unroll
    for (int i = 0; i < 4; ++i) pk[i] = csr[(unsigned)p + 2 * i + half];
#pragma unroll
    for (int i = 0; i < 4; ++i)
      wv[i] = wf[((unsigned)p + 2 * i + half) * 4 + hh];
#pragma unroll
    for (int i = 0; i < 4; ++i)
      fv[i] = featb2[(pk[i] & 0xFFFFFu) * 32 + li];
#pragma unroll
    for (int i = 0; i < 4; ++i) {
      a0 = fmaf(wv[i], __uint_as_float(fv[i].x << 16), a0);
      a1 = fmaf(wv[i], __uint_as_float(fv[i].x & 0xffff0000u), a1);
      a2 = fmaf(wv[i], __uint_as_float(fv[i].y << 16), a2);
      a3 = fmaf(wv[i], __uint_as_float(fv[i].y & 0xffff0000u), a3);
      ds += wv[i];
    }
  }
  if (p < end) {  // predicated tail group (<8 edges)
    const int last = end - 1;
#pragma unroll
    for (int i = 0; i < 4; ++i) {
      const int e = p + 2 * i + (int)half;
      const unsigned ec = (unsigned)min(e, last);
      const unsigned pk = csr[ec];
      float w = wf[ec * 4 + hh];
      if (e > last) w = 0.f;
      const uint2 fv = featb2[(pk & 0xFFFFFu) * 32 + li];
      a0 = fmaf(w, __uint_as_float(fv.x << 16), a0);
      a1 = fmaf(w, __uint_as_float(fv.x & 0xffff0000u), a1);
      a2 = fmaf(w, __uint_as_float(fv.y << 16), a2);
      a3 = fmaf(w, __uint_as_float(fv.y & 0xffff0000u), a3);
      ds += w;
    }
  }

  // combine the two halves
  a0 += __shfl_xor(a0, 32);
  a1 += __shfl_xor(a1, 32);
  a2 += __shfl_xor(a2, 32);
  a3 += __shfl_xor(a3, 32);
  ds += __shfl_xor(ds, 32);

  if (half == 0) {
    const float inv = 1.f / fmaxf(ds, 1e-38f);
    const float4 xr = ((const float4*)x)[(unsigned)n * 32 + li];
    const float4 br = ((const float4*)bias)[li];
    float4 o;
    o.x = fmaf(a0, inv, xr.x + br.x);
    o.y = fmaf(a1, inv, xr.y + br.y);
    o.z = fmaf(a2, inv, xr.z + br.z);
    o.w = fmaf(a3, inv, xr.w + br.w);
    ((float4*)out)[(unsigned)n * 32 + li] = o;
  }
}

// ---------------------------------------------------------------------------
extern "C" void kernel_launch(void* const* d_in, const int* in_sizes, int n_in,
                              void* d_out, int out_size, void* d_ws,
                              size_t ws_size, hipStream_t stream) {
  const float* x      = (const float*)d_in[0];
  const float* fc_w   = (const float*)d_in[1];
  const float* attn_l = (const float*)d_in[2];
  const float* attn_r = (const float*)d_in[3];
  const float* bias   = (const float*)d_in[4];
  const int*   src    = (const int*)d_in[5];
  const int*   dst    = (const int*)d_in[6];
  const int N = in_sizes[0] / 128;
  const int E = in_sizes[5];
  float* out = (float*)d_out;

  const int NB = (N + 255) >> 8;        // 391 buckets (NB <= 512 assumed)
  const int M = NB * PB;                // hist entries
  const int chunk = (E + PB - 1) / PB;  // edges per partition block

  char* ws = (char*)d_ws;
  size_t off = 0;
  auto alloc = [&](size_t bytes) {
    void* p = ws + off;
    off += (bytes + 255) & ~(size_t)255;
    return p;
  };
  unsigned* featb   = (unsigned*)alloc((size_t)N * 128 * 2);
  unsigned* fc_wb   = (unsigned*)alloc(128 * 64 * 4);
  float* el         = (float*)alloc((size_t)N * 4 * 4);
  float* er         = (float*)alloc((size_t)N * 4 * 4);
  int*   hist       = (int*)alloc((size_t)M * 4);
  int*   hscan      = (int*)alloc((size_t)(M + 1) * 4);
  int*   node_offs  = (int*)alloc((size_t)(N + 1) * 4);
  int*   blk_sums   = (int*)alloc(256);
  int*   blk_off    = (int*)alloc(256);
  unsigned* part    = (unsigned*)alloc((size_t)E * 4);
  unsigned* csr     = (unsigned*)alloc((size_t)E * 4);
  float4* wsb       = (float4*)alloc((size_t)E * 16);

  fc_conv<<<32, 256, 0, stream>>>(fc_w, fc_wb, 128 * 64);
  gemm_feat_attn<<<(N + 63) / 64, 256, 0, stream>>>(x, fc_wb, attn_l, attn_r,
                                                    featb, el, er, N);
  hist_bucket<<<PB, 256, 0, stream>>>(dst, hist, E, NB, chunk);
  const int nb = (M + 2047) / 2048;  // 49 (must be <= 64)
  scan_a<<<nb, 256, 0, stream>>>(hist, hscan, blk_sums, M);
  scan_b<<<1, 64, 0, stream>>>(blk_sums, blk_off, hscan, M, nb);
  part_scatter<<<PB, 256, 0, stream>>>(src, dst, hscan, blk_off, part, E, NB,
                                       chunk);
  build_csr<<<NB, 256, 0, stream>>>(part, hscan, blk_off, node_offs, csr, N,
                                    E, NB);
  compute_w<<<NB * WSLICES, 256, 0, stream>>>(csr, hscan, blk_off, el, er,
                                              wsb, E, NB);
  agg_kernel<<<(N + 3) / 4, 256, 0, stream>>>((const uint2*)featb, csr,
                                              (const float*)wsb, x, bias,
                                              node_offs, out, N, E);
}

// Round 9
// 163.100 us; speedup vs baseline: 1.1501x; 1.0432x over previous
//
#include <hip/hip_runtime.h>
#include <math.h>

#define NEG_SLOPE 0.2f
#define PB 256        // partition blocks (fixed chunking shared by hist/scatter)
#define BKT_SHIFT 8   // 256 nodes per bucket
#define WSLICES 8     // blocks per bucket in compute_w

typedef __attribute__((ext_vector_type(8))) short bf16x8;
typedef __attribute__((ext_vector_type(4))) float f32x4;

__device__ __forceinline__ unsigned bf16_rne(float f) {
  unsigned u = __float_as_uint(f);
  return (u + 0x7fff + ((u >> 16) & 1)) >> 16;
}

__device__ __forceinline__ float lrelu_exp(float v) {
  v = v > 0.f ? v : NEG_SLOPE * v;
  return __expf(v);  // no max-subtraction: |v| <~ 10, fp32-safe; normalized
                     // by the denominator so it matches the reference softmax
}

// ---------------------------------------------------------------------------
// MFMA GEMM, hybrid staging: B (fc_wb, 32KB) in LDS -- reused by all 4 waves;
// A (x rows) loaded directly from global -- each row consumed by exactly one
// wave, so LDS staging is pure overhead. Block = 256 thr (4 waves), 64 rows.
// Wave w: rows w*16..+15 x 128 cols (8 col-tiles of 16), K=128 as 4
// MFMA(16x16x32). A/B share the same (g=lane>>4, j)->k convention so any hw
// k-permutation cancels. C/D: col=lane&15, row=(lane>>4)*4+reg (m89-verified).
// ---------------------------------------------------------------------------
__global__ __launch_bounds__(256) void gemm_feat_attn(
    const float* __restrict__ x, const unsigned* __restrict__ fc_wb,
    const float* __restrict__ attn_l, const float* __restrict__ attn_r,
    unsigned* __restrict__ featb, float* __restrict__ el,
    float* __restrict__ er, int N)
{
  __shared__ __align__(16) unsigned w_lds[128 * 68];
  const int t = threadIdx.x;
  const int row_base = blockIdx.x * 64;

  // stage fc_wb words (coalesced uint4): 2048 uint4 total, 8 per thread
  {
    const uint4* fb4 = reinterpret_cast<const uint4*>(fc_wb);
#pragma unroll
    for (int k = 0; k < 8; ++k) {
      const int i4 = t + k * 256;
      const uint4 v = fb4[i4];
      const int row = i4 >> 4;        // 16 uint4 per 64-word row
      unsigned* d = &w_lds[row * 68 + (i4 & 15) * 4];
      d[0] = v.x; d[1] = v.y; d[2] = v.z; d[3] = v.w;
    }
  }

  const int w = t >> 6;         // wave id 0..3
  const int l = t & 63;
  const int cl = l & 15;        // free index (A row / B col / D col)
  const int g = l >> 4;         // k-group

  // A frags direct from global (4 g-lanes x 2 float4 cover 128 contiguous
  // bytes of each row -> full cache-line utilization)
  const int arow = min(row_base + w * 16 + cl, N - 1);
  const float* __restrict__ xp = x + (size_t)arow * 128;
  bf16x8 a_frag[4];
#pragma unroll
  for (int ks = 0; ks < 4; ++ks) {
    const float4 v0 = *reinterpret_cast<const float4*>(xp + ks * 32 + g * 8);
    const float4 v1 =
        *reinterpret_cast<const float4*>(xp + ks * 32 + g * 8 + 4);
    uint4 uu;
    uu.x = bf16_rne(v0.x) | (bf16_rne(v0.y) << 16);
    uu.y = bf16_rne(v0.z) | (bf16_rne(v0.w) << 16);
    uu.z = bf16_rne(v1.x) | (bf16_rne(v1.y) << 16);
    uu.w = bf16_rne(v1.z) | (bf16_rne(v1.w) << 16);
    a_frag[ks] = *reinterpret_cast<bf16x8*>(&uu);
  }
  __syncthreads();

  f32x4 acc[8];
#pragma unroll
  for (int ct = 0; ct < 8; ++ct) acc[ct] = (f32x4){0.f, 0.f, 0.f, 0.f};

#pragma unroll
  for (int ct = 0; ct < 8; ++ct) {
#pragma unroll
    for (int ks = 0; ks < 4; ++ks) {
      const bf16x8 b_frag = *reinterpret_cast<const bf16x8*>(
          &w_lds[(ct * 16 + cl) * 68 + ks * 16 + g * 4]);
      acc[ct] = __builtin_amdgcn_mfma_f32_16x16x32_bf16(a_frag[ks], b_frag,
                                                        acc[ct], 0, 0, 0);
    }
  }

  // featb store: lane holds D[row=g*4+r][col=ct*16+cl]; pair (even,odd cl)
#pragma unroll
  for (int ct = 0; ct < 8; ++ct) {
#pragma unroll
    for (int r = 0; r < 4; ++r) {
      const float v = acc[ct][r];
      const float vn = __shfl_xor(v, 1);
      const int node = row_base + w * 16 + g * 4 + r;
      if ((cl & 1) == 0 && node < N) {
        featb[(size_t)node * 64 + ct * 8 + (cl >> 1)] =
            bf16_rne(v) | (bf16_rne(vn) << 16);
      }
    }
  }

  // el/er epilogue: col 2h*16+cl -> (head h, d=cl); (2h+1)*16+cl -> d=16+cl.
  float al_lo[4], al_hi[4], ar_lo[4], ar_hi[4];
#pragma unroll
  for (int h = 0; h < 4; ++h) {
    al_lo[h] = attn_l[h * 32 + cl];
    al_hi[h] = attn_l[h * 32 + 16 + cl];
    ar_lo[h] = attn_r[h * 32 + cl];
    ar_hi[h] = attn_r[h * 32 + 16 + cl];
  }
#pragma unroll
  for (int r = 0; r < 4; ++r) {
    const int node = row_base + w * 16 + g * 4 + r;
#pragma unroll
    for (int h = 0; h < 4; ++h) {
      float pl = acc[2 * h][r] * al_lo[h] + acc[2 * h + 1][r] * al_hi[h];
      float pr = acc[2 * h][r] * ar_lo[h] + acc[2 * h + 1][r] * ar_hi[h];
#pragma unroll
      for (int d = 1; d < 16; d <<= 1) {
        pl += __shfl_xor(pl, d);
        pr += __shfl_xor(pr, d);
      }
      if (cl == 0 && node < N) {
        el[(size_t)node * 4 + h] = pl;
        er[(size_t)node * 4 + h] = pr;
      }
    }
  }
}

// ---------------------------------------------------------------------------
// CSR build, two-level binning. Bucket = 256 consecutive dst nodes (NB=391).
// First 32 blocks also do the one-shot fc_w -> bf16 conversion (fc_conv fold;
// hist_bucket runs before gemm in the launch order).
// ---------------------------------------------------------------------------
__global__ __launch_bounds__(256) void hist_bucket(const int* __restrict__ dst,
                                                   int* __restrict__ hist,
                                                   const float* __restrict__ fc_w,
                                                   unsigned* __restrict__ fc_wb,
                                                   int E, int NB, int chunk) {
  __shared__ int h[512];
  const int k = blockIdx.x, t = threadIdx.x;
  if (k < 32) {
    const int i = k * 256 + t;
    const float2 v = reinterpret_cast<const float2*>(fc_w)[i];
    fc_wb[i] = bf16_rne(v.x) | (bf16_rne(v.y) << 16);
  }
  for (int i = t; i < NB; i += 256) h[i] = 0;
  __syncthreads();
  const int beg = k * chunk, end = min(E, beg + chunk);
  for (int e = beg + t; e < end; e += 256)
    atomicAdd(&h[dst[e] >> BKT_SHIFT], 1);
  __syncthreads();
  for (int i = t; i < NB; i += 256) hist[i * PB + k] = h[i];
}

__global__ __launch_bounds__(256) void scan_a(const int* __restrict__ deg,
                                              int* __restrict__ offs,
                                              int* __restrict__ blk_sums,
                                              int n) {
  __shared__ int wsum[4];
  const int b = blockIdx.x, t = threadIdx.x;
  const int base = b * 2048 + t * 8;
  int v[8];
  int s = 0;
#pragma unroll
  for (int j = 0; j < 8; ++j) {
    v[j] = s;
    const int d = (base + j < n) ? deg[base + j] : 0;
    s += d;
  }
  const int lane = t & 63;
  int incl = s;
#pragma unroll
  for (int d = 1; d < 64; d <<= 1) {
    const int o = __shfl_up(incl, d);
    if (lane >= d) incl += o;
  }
  const int w = t >> 6;
  if (lane == 63) wsum[w] = incl;
  __syncthreads();
  int woff = 0;
  for (int ww = 0; ww < w; ++ww) woff += wsum[ww];
  const int thr_excl = woff + incl - s;
#pragma unroll
  for (int j = 0; j < 8; ++j)
    if (base + j < n) offs[base + j] = thr_excl + v[j];
  if (t == 255) blk_sums[b] = woff + incl;
}

__global__ void scan_b(const int* __restrict__ blk_sums,
                       int* __restrict__ blk_off, int* __restrict__ offs,
                       int n, int nb) {
  const int lane = threadIdx.x & 63;
  int v = (lane < nb) ? blk_sums[lane] : 0;
  int incl = v;
#pragma unroll
  for (int d = 1; d < 64; d <<= 1) {
    const int o = __shfl_up(incl, d);
    if (lane >= d) incl += o;
  }
  if (lane < nb) blk_off[lane] = incl - v;
  if (lane == 63) offs[n] = incl;
}

// Partition edges into bucket-contiguous regions; per-(bucket,block) region is
// exclusive to this block. Edge packed in 4B: src(20b) | local_dst(8b)<<20.
// hscan is chunk-local; global base = blk_off[idx>>11] added on read.
__global__ __launch_bounds__(256) void part_scatter(
    const int* __restrict__ src, const int* __restrict__ dst,
    const int* __restrict__ hscan, const int* __restrict__ blk_off,
    unsigned* __restrict__ part, int E, int NB, int chunk) {
  __shared__ int cur[512];
  const int k = blockIdx.x, t = threadIdx.x;
  for (int i = t; i < NB; i += 256) {
    const int m = i * PB + k;
    cur[i] = hscan[m] + blk_off[m >> 11];
  }
  __syncthreads();
  const int beg = k * chunk, end = min(E, beg + chunk);
  for (int e = beg + t; e < end; e += 256) {
    const int d = dst[e];
    const int b = d >> BKT_SHIFT;
    const int pos = atomicAdd(&cur[b], 1);
    part[pos] = (unsigned)src[e] |
                ((unsigned)(d & ((1 << BKT_SHIFT) - 1)) << 20);
  }
}

// One block per bucket: LDS count -> scan -> cursor scatter of the PACKED
// word into CSR order. Pure permutation; no per-edge math here.
__global__ __launch_bounds__(256) void build_csr(
    const unsigned* __restrict__ part, const int* __restrict__ hscan,
    const int* __restrict__ blk_off, int* __restrict__ node_offs,
    unsigned* __restrict__ csr, int N, int E, int NB) {
  __shared__ int cnt[256];
  __shared__ int wtot[4];
  const int b = blockIdx.x, t = threadIdx.x;
  const int m0 = b * PB;
  const int bbase = hscan[m0] + blk_off[m0 >> 11];
  int bend = E;
  if (b + 1 < NB) {
    const int m1 = (b + 1) * PB;
    bend = hscan[m1] + blk_off[m1 >> 11];
  }
  const int node0 = b << BKT_SHIFT;
  cnt[t] = 0;
  __syncthreads();
  for (int p = bbase + t; p < bend; p += 256)
    atomicAdd(&cnt[part[p] >> 20], 1);
  __syncthreads();
  const int a0 = cnt[t];
  int incl = a0;
#pragma unroll
  for (int d1 = 1; d1 < 64; d1 <<= 1) {
    const int o = __shfl_up(incl, d1);
    if ((t & 63) >= d1) incl += o;
  }
  const int w = t >> 6;
  if ((t & 63) == 63) wtot[w] = incl;
  __syncthreads();
  int woff = 0;
  for (int ww = 0; ww < w; ++ww) woff += wtot[ww];
  const int e0 = woff + incl - a0;  // exclusive offset of node t
  cnt[t] = e0;                      // reuse as cursor
  if (node0 + t < N) node_offs[node0 + t] = bbase + e0;
  if (b == NB - 1 && t == 0) node_offs[N] = E;
  __syncthreads();
  for (int p = bbase + t; p < bend; p += 256) {
    const unsigned v = part[p];
    const int lpos = atomicAdd(&cnt[v >> 20], 1);
    csr[bbase + lpos] = v;
  }
}

// Edge-parallel over CSR order: wsb[pos] = float4 of per-head numerators
// exp(lrelu(el[s][h]+er[d][h])) (AoS: one 16B line per edge).
__global__ __launch_bounds__(256) void compute_w(
    const unsigned* __restrict__ csr, const int* __restrict__ hscan,
    const int* __restrict__ blk_off, const float* __restrict__ el,
    const float* __restrict__ er, float4* __restrict__ wsb, int E, int NB) {
  const int b = blockIdx.x / WSLICES;
  const int sl = blockIdx.x - b * WSLICES;
  const int m0 = b * PB;
  const int bbase = hscan[m0] + blk_off[m0 >> 11];
  int bend = E;
  if (b + 1 < NB) {
    const int m1 = (b + 1) * PB;
    bend = hscan[m1] + blk_off[m1 >> 11];
  }
  const int node0 = b << BKT_SHIFT;
  const int len = bend - bbase;
  const int per = (len + WSLICES - 1) / WSLICES;
  const int s0 = bbase + sl * per;
  const int s1 = min(bend, s0 + per);
  for (int pos = s0 + (int)threadIdx.x; pos < s1; pos += 256) {
    const unsigned v = csr[pos];
    const unsigned s = v & 0xFFFFFu;
    const unsigned ld = v >> 20;
    const float4 l4 = *reinterpret_cast<const float4*>(el + s * 4);
    const float4 r4 =
        *reinterpret_cast<const float4*>(er + (unsigned)(node0 + ld) * 4);
    float4 wv;
    wv.x = lrelu_exp(l4.x + r4.x);
    wv.y = lrelu_exp(l4.y + r4.y);
    wv.z = lrelu_exp(l4.z + r4.z);
    wv.w = lrelu_exp(l4.w + r4.w);
    wsb[pos] = wv;
  }
}

// ---------------------------------------------------------------------------
// Pull aggregation, half-wave, 16 edges per group (8 per half): wave per
// node; lane l = (half=l>>5, li=l&31). Lane li owns elems {4li..4li+3}
// (uint2 of featb; head = li>>3); half h processes edges p+2i+h. 8 featb
// gathers in flight per lane hide the csr->featb dependent-chain latency.
// Halves combined once per node via shfl_xor(32).
// ---------------------------------------------------------------------------
__global__ __launch_bounds__(256) void agg_kernel(
    const uint2* __restrict__ featb2, const unsigned* __restrict__ csr,
    const float* __restrict__ wf, const float* __restrict__ x,
    const float* __restrict__ bias, const int* __restrict__ node_offs,
    float* __restrict__ out, int N, int E)
{
  const int n = (int)((blockIdx.x * (size_t)blockDim.x + threadIdx.x) >> 6);
  if (n >= N) return;
  const unsigned lane = threadIdx.x & 63;
  const unsigned half = lane >> 5;
  const unsigned li = lane & 31;
  const unsigned hh = li >> 3;        // head of this lane's 4 elems
  const int beg = node_offs[n];
  const int end = node_offs[n + 1];
  const int nfull = (end - beg) >> 4;

  float a0 = 0.f, a1 = 0.f, a2 = 0.f, a3 = 0.f, ds = 0.f;
  int p = beg;
  for (int gi = 0; gi < nfull; ++gi, p += 16) {
    unsigned pk[8]; float wv[8]; uint2 fv[8];
#pragma unroll
    for (int i = 0; i < 8; ++i) pk[i] = csr[(unsigned)p + 2 * i + half];
#pragma unroll
    for (int i = 0; i < 8; ++i)
      wv[i] = wf[((unsigned)p + 2 * i + half) * 4 + hh];
#pragma unroll
    for (int i = 0; i < 8; ++i)
      fv[i] = featb2[(pk[i] & 0xFFFFFu) * 32 + li];
#pragma unroll
    for (int i = 0; i < 8; ++i) {
      a0 = fmaf(wv[i], __uint_as_float(fv[i].x << 16), a0);
      a1 = fmaf(wv[i], __uint_as_float(fv[i].x & 0xffff0000u), a1);
      a2 = fmaf(wv[i], __uint_as_float(fv[i].y << 16), a2);
      a3 = fmaf(wv[i], __uint_as_float(fv[i].y & 0xffff0000u), a3);
      ds += wv[i];
    }
  }
  if (p < end) {  // predicated tail group (<16 edges)
    const int last = end - 1;
    unsigned pk[8]; float wv[8]; uint2 fv[8]; int ee[8];
#pragma unroll
    for (int i = 0; i < 8; ++i) ee[i] = p + 2 * i + (int)half;
#pragma unroll
    for (int i = 0; i < 8; ++i) pk[i] = csr[(unsigned)min(ee[i], last)];
#pragma unroll
    for (int i = 0; i < 8; ++i)
      wv[i] = wf[(unsigned)min(ee[i], last) * 4 + hh];
#pragma unroll
    for (int i = 0; i < 8; ++i)
      fv[i] = featb2[(pk[i] & 0xFFFFFu) * 32 + li];
#pragma unroll
    for (int i = 0; i < 8; ++i) {
      if (ee[i] > last) wv[i] = 0.f;
      a0 = fmaf(wv[i], __uint_as_float(fv[i].x << 16), a0);
      a1 = fmaf(wv[i], __uint_as_float(fv[i].x & 0xffff0000u), a1);
      a2 = fmaf(wv[i], __uint_as_float(fv[i].y << 16), a2);
      a3 = fmaf(wv[i], __uint_as_float(fv[i].y & 0xffff0000u), a3);
      ds += wv[i];
    }
  }

  // combine the two halves
  a0 += __shfl_xor(a0, 32);
  a1 += __shfl_xor(a1, 32);
  a2 += __shfl_xor(a2, 32);
  a3 += __shfl_xor(a3, 32);
  ds += __shfl_xor(ds, 32);

  if (half == 0) {
    const float inv = 1.f / fmaxf(ds, 1e-38f);
    const float4 xr = ((const float4*)x)[(unsigned)n * 32 + li];
    const float4 br = ((const float4*)bias)[li];
    float4 o;
    o.x = fmaf(a0, inv, xr.x + br.x);
    o.y = fmaf(a1, inv, xr.y + br.y);
    o.z = fmaf(a2, inv, xr.z + br.z);
    o.w = fmaf(a3, inv, xr.w + br.w);
    ((float4*)out)[(unsigned)n * 32 + li] = o;
  }
}

// ---------------------------------------------------------------------------
extern "C" void kernel_launch(void* const* d_in, const int* in_sizes, int n_in,
                              void* d_out, int out_size, void* d_ws,
                              size_t ws_size, hipStream_t stream) {
  const float* x      = (const float*)d_in[0];
  const float* fc_w   = (const float*)d_in[1];
  const float* attn_l = (const float*)d_in[2];
  const float* attn_r = (const float*)d_in[3];
  const float* bias   = (const float*)d_in[4];
  const int*   src    = (const int*)d_in[5];
  const int*   dst    = (const int*)d_in[6];
  const int N = in_sizes[0] / 128;
  const int E = in_sizes[5];
  float* out = (float*)d_out;

  const int NB = (N + 255) >> 8;        // 391 buckets (NB <= 512 assumed)
  const int M = NB * PB;                // hist entries
  const int chunk = (E + PB - 1) / PB;  // edges per partition block

  char* ws = (char*)d_ws;
  size_t off = 0;
  auto alloc = [&](size_t bytes) {
    void* p = ws + off;
    off += (bytes + 255) & ~(size_t)255;
    return p;
  };
  unsigned* featb   = (unsigned*)alloc((size_t)N * 128 * 2);
  unsigned* fc_wb   = (unsigned*)alloc(128 * 64 * 4);
  float* el         = (float*)alloc((size_t)N * 4 * 4);
  float* er         = (float*)alloc((size_t)N * 4 * 4);
  int*   hist       = (int*)alloc((size_t)M * 4);
  int*   hscan      = (int*)alloc((size_t)(M + 1) * 4);
  int*   node_offs  = (int*)alloc((size_t)(N + 1) * 4);
  int*   blk_sums   = (int*)alloc(256);
  int*   blk_off    = (int*)alloc(256);
  unsigned* part    = (unsigned*)alloc((size_t)E * 4);
  unsigned* csr     = (unsigned*)alloc((size_t)E * 4);
  float4* wsb       = (float4*)alloc((size_t)E * 16);

  hist_bucket<<<PB, 256, 0, stream>>>(dst, hist, fc_w, fc_wb, E, NB, chunk);
  gemm_feat_attn<<<(N + 63) / 64, 256, 0, stream>>>(x, fc_wb, attn_l, attn_r,
                                                    featb, el, er, N);
  const int nb = (M + 2047) / 2048;  // 49 (must be <= 64)
  scan_a<<<nb, 256, 0, stream>>>(hist, hscan, blk_sums, M);
  scan_b<<<1, 64, 0, stream>>>(blk_sums, blk_off, hscan, M, nb);
  part_scatter<<<PB, 256, 0, stream>>>(src, dst, hscan, blk_off, part, E, NB,
                                       chunk);
  build_csr<<<NB, 256, 0, stream>>>(part, hscan, blk_off, node_offs, csr, N,
                                    E, NB);
  compute_w<<<NB * WSLICES, 256, 0, stream>>>(csr, hscan, blk_off, el, er,
                                              wsb, E, NB);
  agg_kernel<<<(N + 3) / 4, 256, 0, stream>>>((const uint2*)featb, csr,
                                              (const float*)wsb, x, bias,
                                              node_offs, out, N, E);
}